// Round 8
// baseline (1042.770 us; speedup 1.0000x reference)
//
#include <hip/hip_runtime.h>

#define FEAT 128
#define RANGE 12800
#define NSLICE 64

typedef __attribute__((ext_vector_type(2))) float vf2;
typedef __attribute__((ext_vector_type(4))) float vf4;

// ---------- hist: src & dst partial histograms in one dispatch, ushort-packed ----------
__global__ __launch_bounds__(256) void hist_kernel(const int* __restrict__ src,
                                                   const int* __restrict__ dst,
                                                   unsigned* __restrict__ partialD,
                                                   unsigned* __restrict__ partialS,
                                                   int E, int NP) {
    __shared__ unsigned hpk[RANGE / 2];
    int per = (NP / RANGE) * NSLICE;
    int b = blockIdx.x;
    int halfsel = b / per;
    int q = b % per;
    int r = q / NSLICE;
    int s = q % NSLICE;
    const int* arr = halfsel ? src : dst;
    unsigned* out = halfsel ? partialS : partialD;
    int v0 = r * RANGE;
    int tid = threadIdx.x;
    for (int i = tid; i < RANGE / 2; i += 256) hpk[i] = 0;
    __syncthreads();
    int e0 = (int)((long long)E * s / NSLICE);
    int e1 = (int)((long long)E * (s + 1) / NSLICE);
    for (int e = e0 + tid; e < e1; e += 256) {
        unsigned d = (unsigned)(arr[e] - v0);
        if (d < RANGE) atomicAdd(&hpk[d >> 1], (d & 1) ? 65536u : 1u);
    }
    __syncthreads();
    size_t wbase = ((size_t)s * NP + v0) >> 1;
    for (int i = tid; i < RANGE / 2; i += 256) out[wbase + i] = hpk[i];
}

// ---------- scan phase 1: per-node slice-sums + norms ----------
__global__ __launch_bounds__(256) void scanp1_kernel(const unsigned short* __restrict__ pD,
                                                     const unsigned short* __restrict__ pS,
                                                     int* __restrict__ blockSums,
                                                     float* __restrict__ ns,
                                                     float* __restrict__ nd,
                                                     int NP, int n) {
    __shared__ int buf[256];
    int tid = threadIdx.x;
    int v = blockIdx.x * 256 + tid;
    int ssum = 0, osum = 0;
    #pragma unroll
    for (int s = 0; s < NSLICE; ++s) {
        ssum += pD[(size_t)s * NP + v];
        osum += pS[(size_t)s * NP + v];
    }
    if (v < n) {
        ns[v] = 1.0f / sqrtf((float)(osum < 1 ? 1 : osum));
        nd[v] = 1.0f / sqrtf((float)(ssum < 1 ? 1 : ssum));
    }
    buf[tid] = ssum;
    __syncthreads();
    #pragma unroll
    for (int off = 1; off < 256; off <<= 1) {
        int t = (tid >= off) ? buf[tid - off] : 0;
        __syncthreads();
        buf[tid] += t;
        __syncthreads();
    }
    if (tid == 255) blockSums[blockIdx.x] = buf[255];
}

// ---------- scan phase 2 ----------
__global__ __launch_bounds__(256) void scanp2_kernel(const int* __restrict__ blockSums,
                                                     int* __restrict__ blockOffs, int nb) {
    __shared__ int buf[256];
    int tid = threadIdx.x;
    int v = (tid < nb) ? blockSums[tid] : 0;
    buf[tid] = v;
    __syncthreads();
    #pragma unroll
    for (int off = 1; off < 256; off <<= 1) {
        int t = (tid >= off) ? buf[tid - off] : 0;
        __syncthreads();
        buf[tid] += t;
        __syncthreads();
    }
    if (tid < nb) blockOffs[tid] = buf[tid] - v;
}

// ---------- scan phase 3: per-(node,slice) cursors + compact offsets ----------
__global__ __launch_bounds__(256) void scanp3_kernel(const unsigned short* __restrict__ pD,
                                                     const int* __restrict__ blockOffs,
                                                     int* __restrict__ cursorV,
                                                     int* __restrict__ offsc,
                                                     int NP, int n) {
    __shared__ int buf[256];
    int tid = threadIdx.x;
    int v = blockIdx.x * 256 + tid;
    int ssum = 0;
    #pragma unroll
    for (int s = 0; s < NSLICE; ++s) ssum += pD[(size_t)s * NP + v];
    buf[tid] = ssum;
    __syncthreads();
    #pragma unroll
    for (int off = 1; off < 256; off <<= 1) {
        int t = (tid >= off) ? buf[tid - off] : 0;
        __syncthreads();
        buf[tid] += t;
        __syncthreads();
    }
    int o = blockOffs[blockIdx.x] + buf[tid] - ssum;
    if (v <= n) offsc[v] = o;
    int* cv = cursorV + (size_t)v * NSLICE;
    #pragma unroll
    for (int s = 0; s < NSLICE; ++s) {
        int val = pD[(size_t)s * NP + v];
        cv[s] = o;
        o += val;
    }
}

// ---------- prescale: XB[s][v][16] = in_feat[v][s*16..] * ns[v] ----------
__global__ void prescale_kernel(const float* __restrict__ x, const float* __restrict__ ns,
                                float* __restrict__ xb, int n) {
    int i = blockIdx.x * blockDim.x + threadIdx.x;
    if (i >= n * (FEAT / 4)) return;
    int v = i >> 5;
    int q = i & 31;
    float w = ns[v];
    float4 t = ((const float4*)x)[i];
    vf4 tv;
    tv.x = t.x * w; tv.y = t.y * w; tv.z = t.z * w; tv.w = t.w * w;
    int s = q >> 2;
    int cA = (q & 3) * 4;
    __builtin_nontemporal_store(tv, (vf4*)(xb + ((size_t)s * n + v) * 16 + cA));
}

// ---------- fill: place edges via LDS cursors ----------
__global__ __launch_bounds__(256) void fill_kernel(const int* __restrict__ src,
                                                   const int* __restrict__ dst,
                                                   const int* __restrict__ cursorV,
                                                   int* __restrict__ esrc, int E, int NP) {
    __shared__ int cur[RANGE];
    int b = blockIdx.x;
    int r = b / NSLICE;
    int inner = b % NSLICE;
    int s = ((inner & 7) << 3) | (inner >> 3);
    int v0 = r * RANGE;
    int tid = threadIdx.x;
    for (int i = tid; i < RANGE; i += 256)
        cur[i] = cursorV[(size_t)(v0 + i) * NSLICE + s];
    __syncthreads();
    int e0 = (int)((long long)E * s / NSLICE);
    int e1 = (int)((long long)E * (s + 1) / NSLICE);
    for (int e = e0 + tid; e < e1; e += 256) {
        unsigned dd = (unsigned)(dst[e] - v0);
        if (dd < RANGE) {
            int p = atomicAdd(&cur[dd], 1);
            esrc[p] = src[e];
        }
    }
}

// ---------- aggregation: feature-sliced, slice s -> XCD s via blockIdx%8 ----------
// wave = 1 node; 8 lanes x float2 per edge => 8 edges in flight per load instr.
__global__ __launch_bounds__(256) void agg_kernel(const float* __restrict__ xb,
                                                  const int* __restrict__ offs,
                                                  const int* __restrict__ esrc,
                                                  const float* __restrict__ nd,
                                                  float* __restrict__ m, int n) {
    int b = blockIdx.x;
    int s = b & 7;
    int g0 = b >> 3;
    int gstride = gridDim.x >> 3;
    int wave = threadIdx.x >> 6;
    int lane = threadIdx.x & 63;
    int e8 = lane >> 3;
    int c2 = (lane & 7) * 2;
    const float* xs = xb + (size_t)s * n * 16;
    for (int g = g0; g * 4 < n; g += gstride) {
        int v = g * 4 + wave;
        if (v >= n) continue;
        int s0 = offs[v], s1 = offs[v + 1];
        float ax0 = 0.f, ay0 = 0.f, ax1 = 0.f, ay1 = 0.f;
        int j = s0;
        for (; j + 15 < s1; j += 16) {
            int ea = __builtin_nontemporal_load(esrc + j + e8);
            int eb = __builtin_nontemporal_load(esrc + j + 8 + e8);
            float2 ta = *(const float2*)(xs + (size_t)ea * 16 + c2);
            float2 tb = *(const float2*)(xs + (size_t)eb * 16 + c2);
            ax0 += ta.x; ay0 += ta.y;
            ax1 += tb.x; ay1 += tb.y;
        }
        for (; j < s1; j += 8) {
            int idx = j + e8;
            if (idx < s1) {
                int ea = __builtin_nontemporal_load(esrc + idx);
                float2 ta = *(const float2*)(xs + (size_t)ea * 16 + c2);
                ax0 += ta.x; ay0 += ta.y;
            }
        }
        ax0 += ax1; ay0 += ay1;
        ax0 += __shfl_xor(ax0, 8);  ay0 += __shfl_xor(ay0, 8);
        ax0 += __shfl_xor(ax0, 16); ay0 += __shfl_xor(ay0, 16);
        ax0 += __shfl_xor(ax0, 32); ay0 += __shfl_xor(ay0, 32);
        if (e8 == 0) {
            float w = nd[v];
            vf2 r;
            r.x = ax0 * w; r.y = ay0 * w;
            __builtin_nontemporal_store(r, (vf2*)(m + (size_t)v * FEAT + s * 16 + c2));
        }
    }
}

// ---------- GEMM: 128x128 tile, 256 threads, 8x8 acc, reg-prefetch pipeline ----------
// MODE 0: relu*ns, write blocked XB layout.  MODE 1: last layer, row-major h + threshold.
template<int MODE>
__global__ __launch_bounds__(256) void gemm_kernel(const float* __restrict__ M,
                                                   const float* __restrict__ W,
                                                   const float* __restrict__ bias,
                                                   const float* __restrict__ nsv,
                                                   float* __restrict__ out,
                                                   float* __restrict__ out2, int n) {
    __shared__ float MsT[32][132];   // [k][row], stride 132 (16B-aligned)
    __shared__ float Ws[32][128];
    __shared__ float ns_s[128];
    int tid = threadIdx.x;
    int tx = tid & 15;
    int ty = tid >> 4;               // rows ty*8..+7
    int r0 = blockIdx.x * 128;
    if (MODE == 0 && tid < 128) ns_s[tid] = (r0 + tid < n) ? nsv[r0 + tid] : 1.0f;

    float4 wr[4], mr[4];
    int mrow[4], mc4[4];
    #pragma unroll
    for (int i = 0; i < 4; ++i) {
        int idx = tid + i * 256;
        mrow[i] = idx >> 3;
        mc4[i] = idx & 7;
    }
    #pragma unroll
    for (int i = 0; i < 4; ++i)
        wr[i] = ((const float4*)W)[tid + i * 256];
    #pragma unroll
    for (int i = 0; i < 4; ++i) {
        int gr = r0 + mrow[i];
        mr[i] = (gr < n) ? *(const float4*)(M + (size_t)gr * FEAT + mc4[i] * 4)
                         : make_float4(0.f, 0.f, 0.f, 0.f);
    }

    float acc[8][8];
    #pragma unroll
    for (int r = 0; r < 8; ++r)
        #pragma unroll
        for (int i = 0; i < 8; ++i) acc[r][i] = 0.f;

    for (int k0 = 0; k0 < FEAT; k0 += 32) {
        if (k0) __syncthreads();
        #pragma unroll
        for (int i = 0; i < 4; ++i)
            ((float4*)&Ws[0][0])[tid + i * 256] = wr[i];
        #pragma unroll
        for (int i = 0; i < 4; ++i) {
            MsT[mc4[i] * 4 + 0][mrow[i]] = mr[i].x;
            MsT[mc4[i] * 4 + 1][mrow[i]] = mr[i].y;
            MsT[mc4[i] * 4 + 2][mrow[i]] = mr[i].z;
            MsT[mc4[i] * 4 + 3][mrow[i]] = mr[i].w;
        }
        __syncthreads();
        int kn = k0 + 32;
        if (kn < FEAT) {
            #pragma unroll
            for (int i = 0; i < 4; ++i)
                wr[i] = ((const float4*)W)[kn * 32 + tid + i * 256];
            #pragma unroll
            for (int i = 0; i < 4; ++i) {
                int gr = r0 + mrow[i];
                mr[i] = (gr < n) ? *(const float4*)(M + (size_t)gr * FEAT + kn + mc4[i] * 4)
                                 : make_float4(0.f, 0.f, 0.f, 0.f);
            }
        }
        #pragma unroll
        for (int kk = 0; kk < 32; ++kk) {
            float4 a0 = *(const float4*)&MsT[kk][ty * 8];
            float4 a1 = *(const float4*)&MsT[kk][ty * 8 + 4];
            float4 w0 = *(const float4*)&Ws[kk][tx * 4];
            float4 w1 = *(const float4*)&Ws[kk][64 + tx * 4];
            float a[8] = {a0.x, a0.y, a0.z, a0.w, a1.x, a1.y, a1.z, a1.w};
            float w[8] = {w0.x, w0.y, w0.z, w0.w, w1.x, w1.y, w1.z, w1.w};
            #pragma unroll
            for (int r = 0; r < 8; ++r)
                #pragma unroll
                for (int i = 0; i < 8; ++i)
                    acc[r][i] = fmaf(a[r], w[i], acc[r][i]);
        }
    }

    float4 b0 = *(const float4*)&bias[tx * 4];
    float4 b1 = *(const float4*)&bias[64 + tx * 4];
    int sA = tx >> 2;
    int cA = (tx & 3) * 4;
    #pragma unroll
    for (int r = 0; r < 8; ++r) {
        int row = r0 + ty * 8 + r;
        if (row < n) {
            float4 v0, v1;
            v0.x = acc[r][0] + b0.x; v0.y = acc[r][1] + b0.y;
            v0.z = acc[r][2] + b0.z; v0.w = acc[r][3] + b0.w;
            v1.x = acc[r][4] + b1.x; v1.y = acc[r][5] + b1.y;
            v1.z = acc[r][6] + b1.z; v1.w = acc[r][7] + b1.w;
            v0.x = v0.x > 0.f ? v0.x : 0.f; v0.y = v0.y > 0.f ? v0.y : 0.f;
            v0.z = v0.z > 0.f ? v0.z : 0.f; v0.w = v0.w > 0.f ? v0.w : 0.f;
            v1.x = v1.x > 0.f ? v1.x : 0.f; v1.y = v1.y > 0.f ? v1.y : 0.f;
            v1.z = v1.z > 0.f ? v1.z : 0.f; v1.w = v1.w > 0.f ? v1.w : 0.f;
            if (MODE == 0) {
                float sc_ = ns_s[ty * 8 + r];
                vf4 o0, o1;
                o0.x = v0.x * sc_; o0.y = v0.y * sc_; o0.z = v0.z * sc_; o0.w = v0.w * sc_;
                o1.x = v1.x * sc_; o1.y = v1.y * sc_; o1.z = v1.z * sc_; o1.w = v1.w * sc_;
                __builtin_nontemporal_store(o0, (vf4*)(out + ((size_t)sA * n + row) * 16 + cA));
                __builtin_nontemporal_store(o1, (vf4*)(out + ((size_t)(sA + 4) * n + row) * 16 + cA));
            } else {
                *(float4*)(out + (size_t)row * FEAT + tx * 4) = v0;
                *(float4*)(out + (size_t)row * FEAT + 64 + tx * 4) = v1;
                float4 c0, c1;
                c0.x = v0.x >= 0.5f ? 1.f : 0.f; c0.y = v0.y >= 0.5f ? 1.f : 0.f;
                c0.z = v0.z >= 0.5f ? 1.f : 0.f; c0.w = v0.w >= 0.5f ? 1.f : 0.f;
                c1.x = v1.x >= 0.5f ? 1.f : 0.f; c1.y = v1.y >= 0.5f ? 1.f : 0.f;
                c1.z = v1.z >= 0.5f ? 1.f : 0.f; c1.w = v1.w >= 0.5f ? 1.f : 0.f;
                *(float4*)(out2 + (size_t)row * FEAT + tx * 4) = c0;
                *(float4*)(out2 + (size_t)row * FEAT + 64 + tx * 4) = c1;
            }
        }
    }
}

extern "C" void kernel_launch(void* const* d_in, const int* in_sizes, int n_in,
                              void* d_out, int out_size, void* d_ws, size_t ws_size,
                              hipStream_t stream) {
    const float* in_feat = (const float*)d_in[0];
    const int*   src     = (const int*)d_in[1];
    const int*   dst     = (const int*)d_in[2];
    const float* W[5] = {(const float*)d_in[3], (const float*)d_in[5], (const float*)d_in[7],
                         (const float*)d_in[9], (const float*)d_in[11]};
    const float* B[5] = {(const float*)d_in[4], (const float*)d_in[6], (const float*)d_in[8],
                         (const float*)d_in[10], (const float*)d_in[12]};
    const int E = in_sizes[1];
    const int N = in_sizes[0] / FEAT;
    const int NRANGE = (N + RANGE - 1) / RANGE;
    const int NP = NRANGE * RANGE;
    const size_t MTOT = (size_t)NP * NSLICE;

    char* ws = (char*)d_ws;
    size_t off = 0;
    auto alloc = [&](size_t bytes) { size_t o = off; off += (bytes + 255) & ~size_t(255); return o; };
    unsigned* partialD = (unsigned*)(ws + alloc(MTOT * 2));
    size_t    pS_off   = alloc(MTOT * 2);
    unsigned* partialS = (unsigned*)(ws + pS_off);
    int*      esrc     = (int*)(ws + pS_off);          // aliases partialS (dead after scanp1)
    int*      cursorV  = (int*)(ws + alloc(MTOT * 4));
    float*    ns       = (float*)(ws + alloc((size_t)N * 4));
    float*    nd       = (float*)(ws + alloc((size_t)N * 4));
    int*      offsc    = (int*)(ws + alloc((size_t)(N + 1) * 4));
    int*      blockSums = (int*)(ws + alloc(1024));
    int*      blockOffs = (int*)(ws + alloc(1024));

    float* out_h = (float*)d_out;              // m scratch; h5 at the end (in-place)
    float* out_c = out_h + (size_t)N * FEAT;   // XB blocked chain; threshold at the end

    const int histBlocks = 2 * NRANGE * NSLICE;
    const int scanBlocks = NP / 256;
    hist_kernel<<<histBlocks, 256, 0, stream>>>(src, dst, partialD, partialS, E, NP);
    scanp1_kernel<<<scanBlocks, 256, 0, stream>>>((const unsigned short*)partialD,
                                                  (const unsigned short*)partialS,
                                                  blockSums, ns, nd, NP, N);
    scanp2_kernel<<<1, 256, 0, stream>>>(blockSums, blockOffs, scanBlocks);
    scanp3_kernel<<<scanBlocks, 256, 0, stream>>>((const unsigned short*)partialD,
                                                  blockOffs, cursorV, offsc, NP, N);
    prescale_kernel<<<(N * 32 + 255) / 256, 256, 0, stream>>>(in_feat, ns, out_c, N);
    fill_kernel<<<NRANGE * NSLICE, 256, 0, stream>>>(src, dst, cursorV, esrc, E, NP);

    const int agg_blocks = 8 * 3125;           // slice = b%8 -> XCD-local x footprint
    const int gemm_blocks = (N + 127) / 128;

    for (int l = 0; l < 5; ++l) {
        agg_kernel<<<agg_blocks, 256, 0, stream>>>(out_c, offsc, esrc, nd, out_h, N);
        if (l < 4)
            gemm_kernel<0><<<gemm_blocks, 256, 0, stream>>>(out_h, W[l], B[l], ns, out_c, nullptr, N);
        else
            gemm_kernel<1><<<gemm_blocks, 256, 0, stream>>>(out_h, W[l], B[l], ns, out_h, out_c, N);
    }
}

// Round 9
// 997.753 us; speedup vs baseline: 1.0451x; 1.0451x over previous
//
#include <hip/hip_runtime.h>

#define FEAT 128
#define RANGE 12800
#define NSLICE 64

typedef __attribute__((ext_vector_type(4))) float vf4;

// ---------- hist: src & dst partial histograms in one dispatch, ushort-packed ----------
__global__ __launch_bounds__(256) void hist_kernel(const int* __restrict__ src,
                                                   const int* __restrict__ dst,
                                                   unsigned* __restrict__ partialD,
                                                   unsigned* __restrict__ partialS,
                                                   int E, int NP) {
    __shared__ unsigned hpk[RANGE / 2];
    int per = (NP / RANGE) * NSLICE;
    int b = blockIdx.x;
    int halfsel = b / per;
    int q = b % per;
    int r = q / NSLICE;
    int s = q % NSLICE;
    const int* arr = halfsel ? src : dst;
    unsigned* out = halfsel ? partialS : partialD;
    int v0 = r * RANGE;
    int tid = threadIdx.x;
    for (int i = tid; i < RANGE / 2; i += 256) hpk[i] = 0;
    __syncthreads();
    int e0 = (int)((long long)E * s / NSLICE);
    int e1 = (int)((long long)E * (s + 1) / NSLICE);
    for (int e = e0 + tid; e < e1; e += 256) {
        unsigned d = (unsigned)(arr[e] - v0);
        if (d < RANGE) atomicAdd(&hpk[d >> 1], (d & 1) ? 65536u : 1u);
    }
    __syncthreads();
    size_t wbase = ((size_t)s * NP + v0) >> 1;
    for (int i = tid; i < RANGE / 2; i += 256) out[wbase + i] = hpk[i];
}

// ---------- scan phase 1: per-node slice-sums + norms ----------
__global__ __launch_bounds__(256) void scanp1_kernel(const unsigned short* __restrict__ pD,
                                                     const unsigned short* __restrict__ pS,
                                                     int* __restrict__ blockSums,
                                                     float* __restrict__ ns,
                                                     float* __restrict__ nd,
                                                     int NP, int n) {
    __shared__ int buf[256];
    int tid = threadIdx.x;
    int v = blockIdx.x * 256 + tid;
    int ssum = 0, osum = 0;
    #pragma unroll
    for (int s = 0; s < NSLICE; ++s) {
        ssum += pD[(size_t)s * NP + v];
        osum += pS[(size_t)s * NP + v];
    }
    if (v < n) {
        ns[v] = 1.0f / sqrtf((float)(osum < 1 ? 1 : osum));
        nd[v] = 1.0f / sqrtf((float)(ssum < 1 ? 1 : ssum));
    }
    buf[tid] = ssum;
    __syncthreads();
    #pragma unroll
    for (int off = 1; off < 256; off <<= 1) {
        int t = (tid >= off) ? buf[tid - off] : 0;
        __syncthreads();
        buf[tid] += t;
        __syncthreads();
    }
    if (tid == 255) blockSums[blockIdx.x] = buf[255];
}

// ---------- scan phase 2 ----------
__global__ __launch_bounds__(256) void scanp2_kernel(const int* __restrict__ blockSums,
                                                     int* __restrict__ blockOffs, int nb) {
    __shared__ int buf[256];
    int tid = threadIdx.x;
    int v = (tid < nb) ? blockSums[tid] : 0;
    buf[tid] = v;
    __syncthreads();
    #pragma unroll
    for (int off = 1; off < 256; off <<= 1) {
        int t = (tid >= off) ? buf[tid - off] : 0;
        __syncthreads();
        buf[tid] += t;
        __syncthreads();
    }
    if (tid < nb) blockOffs[tid] = buf[tid] - v;
}

// ---------- scan phase 3: per-(node,slice) cursors + compact offsets ----------
__global__ __launch_bounds__(256) void scanp3_kernel(const unsigned short* __restrict__ pD,
                                                     const int* __restrict__ blockOffs,
                                                     int* __restrict__ cursorV,
                                                     int* __restrict__ offsc,
                                                     int NP, int n) {
    __shared__ int buf[256];
    int tid = threadIdx.x;
    int v = blockIdx.x * 256 + tid;
    int ssum = 0;
    #pragma unroll
    for (int s = 0; s < NSLICE; ++s) ssum += pD[(size_t)s * NP + v];
    buf[tid] = ssum;
    __syncthreads();
    #pragma unroll
    for (int off = 1; off < 256; off <<= 1) {
        int t = (tid >= off) ? buf[tid - off] : 0;
        __syncthreads();
        buf[tid] += t;
        __syncthreads();
    }
    int o = blockOffs[blockIdx.x] + buf[tid] - ssum;
    if (v <= n) offsc[v] = o;
    int* cv = cursorV + (size_t)v * NSLICE;
    #pragma unroll
    for (int s = 0; s < NSLICE; ++s) {
        int val = pD[(size_t)s * NP + v];
        cv[s] = o;
        o += val;
    }
}

// ---------- prescale: XB[s][v][16] = in_feat[v][s*16..] * ns[v] ----------
__global__ void prescale_kernel(const float* __restrict__ x, const float* __restrict__ ns,
                                float* __restrict__ xb, int n) {
    int i = blockIdx.x * blockDim.x + threadIdx.x;
    if (i >= n * (FEAT / 4)) return;
    int v = i >> 5;
    int q = i & 31;
    float w = ns[v];
    float4 t = ((const float4*)x)[i];
    vf4 tv;
    tv.x = t.x * w; tv.y = t.y * w; tv.z = t.z * w; tv.w = t.w * w;
    int s = q >> 2;
    int cA = (q & 3) * 4;
    __builtin_nontemporal_store(tv, (vf4*)(xb + ((size_t)s * n + v) * 16 + cA));
}

// ---------- fill: place edges via LDS cursors ----------
__global__ __launch_bounds__(256) void fill_kernel(const int* __restrict__ src,
                                                   const int* __restrict__ dst,
                                                   const int* __restrict__ cursorV,
                                                   int* __restrict__ esrc, int E, int NP) {
    __shared__ int cur[RANGE];
    int b = blockIdx.x;
    int r = b / NSLICE;
    int inner = b % NSLICE;
    int s = ((inner & 7) << 3) | (inner >> 3);
    int v0 = r * RANGE;
    int tid = threadIdx.x;
    for (int i = tid; i < RANGE; i += 256)
        cur[i] = cursorV[(size_t)(v0 + i) * NSLICE + s];
    __syncthreads();
    int e0 = (int)((long long)E * s / NSLICE);
    int e1 = (int)((long long)E * (s + 1) / NSLICE);
    for (int e = e0 + tid; e < e1; e += 256) {
        unsigned dd = (unsigned)(dst[e] - v0);
        if (dd < RANGE) {
            int p = atomicAdd(&cur[dd], 1);
            esrc[p] = src[e];
        }
    }
}

// ---------- aggregation: one wave per (node, slice), 16 edges in flight ----------
// lanes = 16 edge-groups x 4 lanes; each group loads one edge's 64B slice (float4/lane).
// slice = blockIdx&7 -> XCD-local x footprint (3.2 MB, L2-resident); esrc streamed nt.
__global__ __launch_bounds__(256) void agg_kernel(const float* __restrict__ xb,
                                                  const int* __restrict__ offs,
                                                  const int* __restrict__ esrc,
                                                  const float* __restrict__ nd,
                                                  float* __restrict__ m, int n) {
    int b = blockIdx.x;
    int s = b & 7;
    int g = b >> 3;
    int wave = threadIdx.x >> 6;
    int lane = threadIdx.x & 63;
    int eg = lane >> 2;          // edge group 0..15
    int c4 = (lane & 3) * 4;     // float4 column within 16-float slice
    int v = g * 4 + wave;
    if (v >= n) return;
    const float* xs = xb + (size_t)s * n * 16;
    int s0 = offs[v], s1 = offs[v + 1];
    float ax = 0.f, ay = 0.f, az = 0.f, aw = 0.f;
    for (int j = s0; j < s1; j += 16) {
        int idx = j + eg;
        int clamped = idx < s1 ? idx : s1 - 1;
        int e = __builtin_nontemporal_load(esrc + clamped);
        float4 t = *(const float4*)(xs + (size_t)e * 16 + c4);
        if (idx < s1) { ax += t.x; ay += t.y; az += t.z; aw += t.w; }
    }
    // reduce across the 16 edge groups
    #pragma unroll
    for (int mask = 4; mask <= 32; mask <<= 1) {
        ax += __shfl_xor(ax, mask);
        ay += __shfl_xor(ay, mask);
        az += __shfl_xor(az, mask);
        aw += __shfl_xor(aw, mask);
    }
    if (lane < 4) {
        float w = nd[v];
        vf4 r;
        r.x = ax * w; r.y = ay * w; r.z = az * w; r.w = aw * w;
        __builtin_nontemporal_store(r, (vf4*)(m + (size_t)v * FEAT + s * 16 + c4));
    }
}

// ---------- GEMM: 128x128 tile, 256 threads, 8x8 acc, reg-prefetch pipeline ----------
template<int MODE>
__global__ __launch_bounds__(256) void gemm_kernel(const float* __restrict__ M,
                                                   const float* __restrict__ W,
                                                   const float* __restrict__ bias,
                                                   const float* __restrict__ nsv,
                                                   float* __restrict__ out,
                                                   float* __restrict__ out2, int n) {
    __shared__ float MsT[32][132];
    __shared__ float Ws[32][128];
    __shared__ float ns_s[128];
    int tid = threadIdx.x;
    int tx = tid & 15;
    int ty = tid >> 4;
    int r0 = blockIdx.x * 128;
    if (MODE == 0 && tid < 128) ns_s[tid] = (r0 + tid < n) ? nsv[r0 + tid] : 1.0f;

    float4 wr[4], mr[4];
    int mrow[4], mc4[4];
    #pragma unroll
    for (int i = 0; i < 4; ++i) {
        int idx = tid + i * 256;
        mrow[i] = idx >> 3;
        mc4[i] = idx & 7;
    }
    #pragma unroll
    for (int i = 0; i < 4; ++i)
        wr[i] = ((const float4*)W)[tid + i * 256];
    #pragma unroll
    for (int i = 0; i < 4; ++i) {
        int gr = r0 + mrow[i];
        mr[i] = (gr < n) ? *(const float4*)(M + (size_t)gr * FEAT + mc4[i] * 4)
                         : make_float4(0.f, 0.f, 0.f, 0.f);
    }

    float acc[8][8];
    #pragma unroll
    for (int r = 0; r < 8; ++r)
        #pragma unroll
        for (int i = 0; i < 8; ++i) acc[r][i] = 0.f;

    for (int k0 = 0; k0 < FEAT; k0 += 32) {
        if (k0) __syncthreads();
        #pragma unroll
        for (int i = 0; i < 4; ++i)
            ((float4*)&Ws[0][0])[tid + i * 256] = wr[i];
        #pragma unroll
        for (int i = 0; i < 4; ++i) {
            MsT[mc4[i] * 4 + 0][mrow[i]] = mr[i].x;
            MsT[mc4[i] * 4 + 1][mrow[i]] = mr[i].y;
            MsT[mc4[i] * 4 + 2][mrow[i]] = mr[i].z;
            MsT[mc4[i] * 4 + 3][mrow[i]] = mr[i].w;
        }
        __syncthreads();
        int kn = k0 + 32;
        if (kn < FEAT) {
            #pragma unroll
            for (int i = 0; i < 4; ++i)
                wr[i] = ((const float4*)W)[kn * 32 + tid + i * 256];
            #pragma unroll
            for (int i = 0; i < 4; ++i) {
                int gr = r0 + mrow[i];
                mr[i] = (gr < n) ? *(const float4*)(M + (size_t)gr * FEAT + kn + mc4[i] * 4)
                                 : make_float4(0.f, 0.f, 0.f, 0.f);
            }
        }
        #pragma unroll
        for (int kk = 0; kk < 32; ++kk) {
            float4 a0 = *(const float4*)&MsT[kk][ty * 8];
            float4 a1 = *(const float4*)&MsT[kk][ty * 8 + 4];
            float4 w0 = *(const float4*)&Ws[kk][tx * 4];
            float4 w1 = *(const float4*)&Ws[kk][64 + tx * 4];
            float a[8] = {a0.x, a0.y, a0.z, a0.w, a1.x, a1.y, a1.z, a1.w};
            float w[8] = {w0.x, w0.y, w0.z, w0.w, w1.x, w1.y, w1.z, w1.w};
            #pragma unroll
            for (int r = 0; r < 8; ++r)
                #pragma unroll
                for (int i = 0; i < 8; ++i)
                    acc[r][i] = fmaf(a[r], w[i], acc[r][i]);
        }
    }

    float4 b0 = *(const float4*)&bias[tx * 4];
    float4 b1 = *(const float4*)&bias[64 + tx * 4];
    int sA = tx >> 2;
    int cA = (tx & 3) * 4;
    #pragma unroll
    for (int r = 0; r < 8; ++r) {
        int row = r0 + ty * 8 + r;
        if (row < n) {
            float4 v0, v1;
            v0.x = acc[r][0] + b0.x; v0.y = acc[r][1] + b0.y;
            v0.z = acc[r][2] + b0.z; v0.w = acc[r][3] + b0.w;
            v1.x = acc[r][4] + b1.x; v1.y = acc[r][5] + b1.y;
            v1.z = acc[r][6] + b1.z; v1.w = acc[r][7] + b1.w;
            v0.x = v0.x > 0.f ? v0.x : 0.f; v0.y = v0.y > 0.f ? v0.y : 0.f;
            v0.z = v0.z > 0.f ? v0.z : 0.f; v0.w = v0.w > 0.f ? v0.w : 0.f;
            v1.x = v1.x > 0.f ? v1.x : 0.f; v1.y = v1.y > 0.f ? v1.y : 0.f;
            v1.z = v1.z > 0.f ? v1.z : 0.f; v1.w = v1.w > 0.f ? v1.w : 0.f;
            if (MODE == 0) {
                float sc_ = ns_s[ty * 8 + r];
                vf4 o0, o1;
                o0.x = v0.x * sc_; o0.y = v0.y * sc_; o0.z = v0.z * sc_; o0.w = v0.w * sc_;
                o1.x = v1.x * sc_; o1.y = v1.y * sc_; o1.z = v1.z * sc_; o1.w = v1.w * sc_;
                __builtin_nontemporal_store(o0, (vf4*)(out + ((size_t)sA * n + row) * 16 + cA));
                __builtin_nontemporal_store(o1, (vf4*)(out + ((size_t)(sA + 4) * n + row) * 16 + cA));
            } else {
                *(float4*)(out + (size_t)row * FEAT + tx * 4) = v0;
                *(float4*)(out + (size_t)row * FEAT + 64 + tx * 4) = v1;
                float4 c0, c1;
                c0.x = v0.x >= 0.5f ? 1.f : 0.f; c0.y = v0.y >= 0.5f ? 1.f : 0.f;
                c0.z = v0.z >= 0.5f ? 1.f : 0.f; c0.w = v0.w >= 0.5f ? 1.f : 0.f;
                c1.x = v1.x >= 0.5f ? 1.f : 0.f; c1.y = v1.y >= 0.5f ? 1.f : 0.f;
                c1.z = v1.z >= 0.5f ? 1.f : 0.f; c1.w = v1.w >= 0.5f ? 1.f : 0.f;
                *(float4*)(out2 + (size_t)row * FEAT + tx * 4) = c0;
                *(float4*)(out2 + (size_t)row * FEAT + 64 + tx * 4) = c1;
            }
        }
    }
}

extern "C" void kernel_launch(void* const* d_in, const int* in_sizes, int n_in,
                              void* d_out, int out_size, void* d_ws, size_t ws_size,
                              hipStream_t stream) {
    const float* in_feat = (const float*)d_in[0];
    const int*   src     = (const int*)d_in[1];
    const int*   dst     = (const int*)d_in[2];
    const float* W[5] = {(const float*)d_in[3], (const float*)d_in[5], (const float*)d_in[7],
                         (const float*)d_in[9], (const float*)d_in[11]};
    const float* B[5] = {(const float*)d_in[4], (const float*)d_in[6], (const float*)d_in[8],
                         (const float*)d_in[10], (const float*)d_in[12]};
    const int E = in_sizes[1];
    const int N = in_sizes[0] / FEAT;
    const int NRANGE = (N + RANGE - 1) / RANGE;
    const int NP = NRANGE * RANGE;
    const size_t MTOT = (size_t)NP * NSLICE;

    char* ws = (char*)d_ws;
    size_t off = 0;
    auto alloc = [&](size_t bytes) { size_t o = off; off += (bytes + 255) & ~size_t(255); return o; };
    unsigned* partialD = (unsigned*)(ws + alloc(MTOT * 2));
    size_t    pS_off   = alloc(MTOT * 2);
    unsigned* partialS = (unsigned*)(ws + pS_off);
    int*      esrc     = (int*)(ws + pS_off);
    int*      cursorV  = (int*)(ws + alloc(MTOT * 4));
    float*    ns       = (float*)(ws + alloc((size_t)N * 4));
    float*    nd       = (float*)(ws + alloc((size_t)N * 4));
    int*      offsc    = (int*)(ws + alloc((size_t)(N + 1) * 4));
    int*      blockSums = (int*)(ws + alloc(1024));
    int*      blockOffs = (int*)(ws + alloc(1024));

    float* out_h = (float*)d_out;
    float* out_c = out_h + (size_t)N * FEAT;

    const int histBlocks = 2 * NRANGE * NSLICE;
    const int scanBlocks = NP / 256;
    hist_kernel<<<histBlocks, 256, 0, stream>>>(src, dst, partialD, partialS, E, NP);
    scanp1_kernel<<<scanBlocks, 256, 0, stream>>>((const unsigned short*)partialD,
                                                  (const unsigned short*)partialS,
                                                  blockSums, ns, nd, NP, N);
    scanp2_kernel<<<1, 256, 0, stream>>>(blockSums, blockOffs, scanBlocks);
    scanp3_kernel<<<scanBlocks, 256, 0, stream>>>((const unsigned short*)partialD,
                                                  blockOffs, cursorV, offsc, NP, N);
    prescale_kernel<<<(N * 32 + 255) / 256, 256, 0, stream>>>(in_feat, ns, out_c, N);
    fill_kernel<<<NRANGE * NSLICE, 256, 0, stream>>>(src, dst, cursorV, esrc, E, NP);

    const int agg_blocks = 8 * ((N + 3) / 4);   // wave per (node, slice); slice = b&7
    const int gemm_blocks = (N + 127) / 128;

    for (int l = 0; l < 5; ++l) {
        agg_kernel<<<agg_blocks, 256, 0, stream>>>(out_c, offsc, esrc, nd, out_h, N);
        if (l < 4)
            gemm_kernel<0><<<gemm_blocks, 256, 0, stream>>>(out_h, W[l], B[l], ns, out_c, nullptr, N);
        else
            gemm_kernel<1><<<gemm_blocks, 256, 0, stream>>>(out_h, W[l], B[l], ns, out_h, out_c, N);
    }
}